// Round 2
// baseline (204.414 us; speedup 1.0000x reference)
//
#include <hip/hip_runtime.h>
#include <stdint.h>

typedef unsigned long long u64;
typedef unsigned int u32;

#define VOCAB 128000
#define NV4   32000      // VOCAB/4
#define NROWS 256
#define BLK   1024
#define NB    4096
#define SEPS  1e-5f
#define FIXS  17592186044416.0  /* 2^44 fixed-point scale for prob masses */

// ---------- helpers ----------
__device__ __forceinline__ u32 f2key(float f){
  u32 u = __float_as_uint(f);
  return (u & 0x80000000u) ? ~u : (u | 0x80000000u);   // order-preserving map
}
__device__ __forceinline__ float key2f(u32 k){
  u32 u = (k & 0x80000000u) ? (k ^ 0x80000000u) : ~k;
  return __uint_as_float(u);
}
__device__ __forceinline__ u64 efix(float e){
  return (u64)((double)e * FIXS);   // e in [0,1]; exact in double, truncate
}

// JAX threefry2x32 with key (0,42)  (jax.random.key(42))
__device__ __forceinline__ void tf2x32(u32 x0, u32 x1, u32 &o0, u32 &o1){
  const u32 k0 = 0u, k1 = 42u, k2 = 0u ^ 42u ^ 0x1BD11BDAu;
  x0 += k0; x1 += k1;
#define TFR(r) { x0 += x1; x1 = (x1 << (r)) | (x1 >> (32 - (r))); x1 ^= x0; }
  TFR(13) TFR(15) TFR(26) TFR(6)
  x0 += k1; x1 += k2 + 1u;
  TFR(17) TFR(29) TFR(16) TFR(24)
  x0 += k2; x1 += k0 + 2u;
  TFR(13) TFR(15) TFR(26) TFR(6)
  x0 += k0; x1 += k1 + 3u;
  TFR(17) TFR(29) TFR(16) TFR(24)
  x0 += k1; x1 += k2 + 4u;
  TFR(13) TFR(15) TFR(26) TFR(6)
  x0 += k2; x1 += k0 + 5u;
#undef TFR
  o0 = x0; o1 = x1;
}

// JAX partitionable threefry (default since jax 0.4.30): element linear index i
// (fits 32 bits here) -> threefry2x32(key, (0, i)); 32-bit stream = o0 ^ o1.
__device__ __forceinline__ u32 gumbel_bits(u32 i){
  u32 o0, o1; tf2x32(0u, i, o0, o1);
  return o0 ^ o1;
}

// bits -> jax.random.uniform(1e-10,1.0) -> gumbel.  (1.0f-1e-10f)==1.0f in f32.
__device__ __forceinline__ float bits2gumbel(u32 b){
  float f = __uint_as_float(0x3F800000u | (b >> 9)) - 1.0f;  // [0,1)
  float u = fmaxf(1e-10f, f + 1e-10f);
  return -logf(-logf(u));
}

// inclusive scans over NB entries in LDS (deterministic)
__device__ void scan_incl_u32(u32* a, u32* aux, int t){
  int base = t * 4;
  u32 x0=a[base], x1=a[base+1], x2=a[base+2], x3=a[base+3];
  x1 += x0; x2 += x1; x3 += x2;
  a[base]=x0; a[base+1]=x1; a[base+2]=x2; a[base+3]=x3;
  aux[t] = x3;
  __syncthreads();
  for (int off=1; off<BLK; off<<=1){
    u32 add = (t >= off) ? aux[t-off] : 0u;
    __syncthreads();
    aux[t] += add;
    __syncthreads();
  }
  u32 ex = t ? aux[t-1] : 0u;
  a[base]+=ex; a[base+1]+=ex; a[base+2]+=ex; a[base+3]+=ex;
  __syncthreads();
}
__device__ void scan_incl_u64(u64* a, u64* aux, int t){
  int base = t * 4;
  u64 x0=a[base], x1=a[base+1], x2=a[base+2], x3=a[base+3];
  x1 += x0; x2 += x1; x3 += x2;
  a[base]=x0; a[base+1]=x1; a[base+2]=x2; a[base+3]=x3;
  aux[t] = x3;
  __syncthreads();
  for (int off=1; off<BLK; off<<=1){
    u64 add = (t >= off) ? aux[t-off] : 0ULL;
    __syncthreads();
    aux[t] += add;
    __syncthreads();
  }
  u64 ex = t ? aux[t-1] : 0ULL;
  a[base]+=ex; a[base+1]+=ex; a[base+2]+=ex; a[base+3]+=ex;
  __syncthreads();
}

// ---------- kernel 1: per-row stats + 3-level radix select of thresholds ----------
__global__ __launch_bounds__(BLK) void k_prep(
    const float* __restrict__ logits, const float* __restrict__ temp,
    const float* __restrict__ minp, const int* __restrict__ topk,
    const float* __restrict__ topp,
    float* __restrict__ wsm, float* __restrict__ wsz,
    float* __restrict__ wsr, float* __restrict__ wst, int* __restrict__ wsg)
{
  __shared__ u32 cnt[NB];
  __shared__ u64 mass[NB];
  __shared__ u32 aux32[BLK];
  __shared__ u64 aux64[BLK];
  __shared__ float redv[BLK]; __shared__ u32 redi[BLK];
  __shared__ float redm[BLK]; __shared__ float redS[BLK];
  __shared__ float sh_m, sh_Z, sh_rhs;
  __shared__ u32 sh_b1k, sh_b1p, sh_b2k, sh_b2p, sh_b3k, sh_b3p, sh_r1, sh_r2;
  __shared__ u64 sh_t1, sh_t2;

  const int b = blockIdx.x;
  const int t = threadIdx.x;
  const float T = temp[b];
  const bool greedy = (T < SEPS);
  const float st = greedy ? 1.0f : T;
  const float* row = logits + (size_t)b * VOCAB;
  const float4* row4 = (const float4*)row;

  // ---- P1: max logit + argmax (greedy) + online softmax-sum Z of scaled ----
  float M = -INFINITY; u32 Mi = 0u;
  float ms = -INFINITY, S = 0.0f;
  for (int i=t; i<NV4; i+=BLK){
    float4 q = row4[i];
    float vv[4] = {q.x,q.y,q.z,q.w};
    #pragma unroll
    for (int j=0;j<4;j++){
      float l = vv[j];
      u32 gi = (u32)(i*4+j);
      if (l > M){ M = l; Mi = gi; }
      float s = l / st;
      if (s > ms){ S = S*expf(ms - s) + 1.0f; ms = s; }
      else       { S += expf(s - ms); }
    }
  }
  redv[t]=M; redi[t]=Mi; redm[t]=ms; redS[t]=S;
  __syncthreads();
  for (int off=BLK>>1; off>0; off>>=1){
    if (t < off){
      float M2=redv[t+off]; u32 I2=redi[t+off];
      if (M2 > redv[t] || (M2 == redv[t] && I2 < redi[t])){ redv[t]=M2; redi[t]=I2; }
      float m1=redm[t], S1=redS[t];
      float m2=redm[t+off], S2=redS[t+off];
      float mm = fmaxf(m1,m2);
      redS[t] = S1*expf(m1-mm) + S2*expf(m2-mm);
      redm[t] = mm;
    }
    __syncthreads();
  }
  if (t==0){
    sh_m = redm[0]; sh_Z = redS[0];
    sh_rhs = minp[b] * (1.0f / sh_Z);     // min_p * max_prob, max_prob = fl(1/Z)
    wsm[b]=sh_m; wsz[b]=sh_Z; wsr[b]=sh_rhs;
    wsg[b]=(int)redi[0];
    sh_b1k=0u; sh_b1p=0u; sh_b2k=0u; sh_b2p=0u; sh_b3k=0u; sh_b3p=0u;
    sh_r1=1u; sh_r2=1u; sh_t1=0ULL; sh_t2=0ULL;
  }
  __syncthreads();
  if (greedy){ if (t==0) wst[b] = INFINITY; return; }
  const float m = sh_m, Z = sh_Z, rhs = sh_rhs;

  // ---- P2: level-1 histogram (top 12 bits of ordered key), kept tokens only ----
  for (int i=t;i<NB;i+=BLK){ cnt[i]=0u; mass[i]=0ULL; }
  __syncthreads();
  for (int i=t; i<NV4; i+=BLK){
    float4 q = row4[i];
    float vv[4]={q.x,q.y,q.z,q.w};
    #pragma unroll
    for (int j=0;j<4;j++){
      float s = vv[j] / st;
      float e = expf(s - m);
      if ((e / Z) >= rhs){
        u32 k = f2key(s);
        atomicAdd(&cnt[k>>20], 1u);
        atomicAdd(&mass[k>>20], efix(e));
      }
    }
  }
  __syncthreads();
  scan_incl_u32(cnt, aux32, t);
  scan_incl_u64(mass, aux64, t);
  const u32 K    = cnt[NB-1];         // kept count
  const u64 Mtot = mass[NB-1];        // total kept mass (fixed point)
  const int tk = topk[b];
  const long R = (long)K - (long)tk + 1;   // ascending rank of kth largest among kept
  const int kval = (R >= 1);               // else k_thresh = -inf
  const u64 tfix = (u64)((double)(1.0f - topp[b]) * (double)Mtot);
  for (int i=t;i<NB;i+=BLK){
    if (kval && (long)cnt[i] >= R && (long)(i?cnt[i-1]:0u) < R) sh_b1k = (u32)i;
    if (mass[i] > tfix && (i?mass[i-1]:0ULL) <= tfix)           sh_b1p = (u32)i;
  }
  __syncthreads();
  if (t==0){
    if (kval) sh_r1 = (u32)(R - (long)(sh_b1k ? cnt[sh_b1k-1] : 0u));
    sh_t1 = tfix - (sh_b1p ? mass[sh_b1p-1] : 0ULL);
  }
  __syncthreads();
  const u32 b1k = sh_b1k, b1p = sh_b1p;
  const u32 r1 = sh_r1; const u64 t1 = sh_t1;

  // ---- P3: level-2 histogram (bits 19..8) within selected level-1 buckets ----
  __syncthreads();
  for (int i=t;i<NB;i+=BLK){ cnt[i]=0u; mass[i]=0ULL; }
  __syncthreads();
  for (int i=t; i<NV4; i+=BLK){
    float4 q = row4[i];
    float vv[4]={q.x,q.y,q.z,q.w};
    #pragma unroll
    for (int j=0;j<4;j++){
      float s = vv[j] / st;
      u32 k = f2key(s);
      u32 hi = k >> 20;
      bool ck = kval && (hi == b1k);
      bool cp = (hi == b1p);
      if (ck | cp){                       // expf only for candidate buckets
        float e = expf(s - m);
        if ((e / Z) >= rhs){
          if (ck) atomicAdd(&cnt[(k>>8)&0xFFFu], 1u);
          if (cp) atomicAdd(&mass[(k>>8)&0xFFFu], efix(e));
        }
      }
    }
  }
  __syncthreads();
  scan_incl_u32(cnt, aux32, t);
  scan_incl_u64(mass, aux64, t);
  for (int i=t;i<NB;i+=BLK){
    if (kval && cnt[i] >= r1 && (i?cnt[i-1]:0u) < r1) sh_b2k = (u32)i;
    if (mass[i] > t1 && (i?mass[i-1]:0ULL) <= t1)     sh_b2p = (u32)i;
  }
  __syncthreads();
  if (t==0){
    if (kval) sh_r2 = r1 - (sh_b2k ? cnt[sh_b2k-1] : 0u);
    sh_t2 = t1 - (sh_b2p ? mass[sh_b2p-1] : 0ULL);
  }
  __syncthreads();
  const u32 b2k = sh_b2k, b2p = sh_b2p, r2 = sh_r2; const u64 t2 = sh_t2;
  const u32 prefk = (b1k << 12) | b2k;   // 24-bit prefix
  const u32 prefp = (b1p << 12) | b2p;

  // ---- P4: level-3 histogram (low 8 bits) -> exact threshold values ----
  __syncthreads();
  for (int i=t;i<256;i+=BLK){ cnt[i]=0u; mass[i]=0ULL; }
  __syncthreads();
  for (int i=t; i<NV4; i+=BLK){
    float4 q = row4[i];
    float vv[4]={q.x,q.y,q.z,q.w};
    #pragma unroll
    for (int j=0;j<4;j++){
      float s = vv[j] / st;
      u32 k = f2key(s);
      u32 top = k >> 8;
      bool ck = kval && (top == prefk);
      bool cp = (top == prefp);
      if (ck | cp){                       // expf only for candidate buckets
        float e = expf(s - m);
        if ((e / Z) >= rhs){
          if (ck) atomicAdd(&cnt[k & 0xFFu], 1u);
          if (cp) atomicAdd(&mass[k & 0xFFu], efix(e));
        }
      }
    }
  }
  __syncthreads();
  for (int off=1; off<256; off<<=1){
    u32 ca = 0u; u64 ma = 0ULL;
    if (t < 256 && t >= off){ ca = cnt[t-off]; ma = mass[t-off]; }
    __syncthreads();
    if (t < 256 && t >= off){ cnt[t] += ca; mass[t] += ma; }
    __syncthreads();
  }
  if (t < 256){
    if (kval && cnt[t] >= r2 && (t==0 || cnt[t-1] < r2)) sh_b3k = (u32)t;
    if (mass[t] > t2 && (t==0 || mass[t-1] <= t2))       sh_b3p = (u32)t;
  }
  __syncthreads();
  if (t==0){
    float kth = kval ? key2f((prefk << 8) | sh_b3k) : -INFINITY;
    float pth = key2f((prefp << 8) | sh_b3p);
    wst[b] = fmaxf(kth, pth);
  }
}

// ---------- kernel 2: gumbel-max over the (<= ~top_k) surviving tokens ----------
// one block per row; only tokens passing (s >= thresh) pay threefry + logs.
__global__ __launch_bounds__(BLK) void k_sample(
    const float* __restrict__ logits, const float* __restrict__ temp,
    const float* __restrict__ wsm, const float* __restrict__ wsz,
    const float* __restrict__ wsr, const float* __restrict__ wst,
    const int* __restrict__ wsg, int* __restrict__ out)
{
  const int r = blockIdx.x;
  const int t = threadIdx.x;
  __shared__ float rv[BLK]; __shared__ u32 ri[BLK];
  const float T = temp[r];
  if (T < SEPS){ if (t==0) out[r] = wsg[r]; return; }
  const float st = T;
  const float m=wsm[r], Z=wsz[r], rh=wsr[r], th=wst[r];
  const float* row = logits + (size_t)r * VOCAB;
  const float4* row4 = (const float4*)row;
  float best=-INFINITY; u32 bi=0xFFFFFFFFu;

  for (int i=t; i<NV4; i+=BLK){
    float4 q = row4[i];
    float vv[4]={q.x,q.y,q.z,q.w};
    #pragma unroll
    for (int j=0;j<4;j++){
      float s = vv[j] / st;
      if (s >= th){                          // rare (<= ~top_k per row)
        float e = expf(s - m);
        if ((e / Z) >= rh){
          u32 idx = (u32)(i*4+j);
          u32 c = (u32)r * (u32)VOCAB + idx; // linear element index (< 2^32)
          float cand = s + bits2gumbel(gumbel_bits(c));
          if (cand > best || (cand == best && idx < bi)){ best=cand; bi=idx; }
        }
      }
    }
  }
  rv[t]=best; ri[t]=bi;
  __syncthreads();
  for (int off=BLK>>1; off>0; off>>=1){
    if (t < off){
      if (rv[t+off] > rv[t] || (rv[t+off]==rv[t] && ri[t+off] < ri[t])){
        rv[t]=rv[t+off]; ri[t]=ri[t+off];
      }
    }
    __syncthreads();
  }
  if (t==0) out[r] = (int)ri[0];
}

extern "C" void kernel_launch(void* const* d_in, const int* in_sizes, int n_in,
                              void* d_out, int out_size, void* d_ws, size_t ws_size,
                              hipStream_t stream)
{
  const float* logits = (const float*)d_in[0];
  const float* temp   = (const float*)d_in[1];
  const float* minp   = (const float*)d_in[2];
  const int*   topk   = (const int*)d_in[3];
  const float* topp   = (const float*)d_in[4];

  char* ws = (char*)d_ws;
  float* wsm = (float*)(ws + 0);       // [256] row max of scaled
  float* wsz = (float*)(ws + 1024);    // [256] softmax denom Z
  float* wsr = (float*)(ws + 2048);    // [256] min_p * max_prob
  float* wst = (float*)(ws + 3072);    // [256] final threshold
  int*   wsg = (int*)(ws + 4096);      // [256] greedy argmax

  int* out = (int*)d_out;

  hipLaunchKernelGGL(k_prep,   dim3(NROWS), dim3(BLK), 0, stream,
                     logits, temp, minp, topk, topp, wsm, wsz, wsr, wst, wsg);
  hipLaunchKernelGGL(k_sample, dim3(NROWS), dim3(BLK), 0, stream,
                     logits, temp, wsm, wsz, wsr, wst, wsg, out);
}

// Round 3
// 137.710 us; speedup vs baseline: 1.4844x; 1.4844x over previous
//
#include <hip/hip_runtime.h>
#include <stdint.h>

typedef unsigned long long u64;
typedef unsigned int u32;

#define VOCAB 128000
#define NV4   32000      // VOCAB/4
#define NROWS 256
#define BLK   1024
#define NB    4096
#define SEPS  1e-5f
#define FIXS  17592186044416.0  /* 2^44 fixed-point scale for prob masses */

// ---------- helpers ----------
__device__ __forceinline__ u32 f2key(float f){
  u32 u = __float_as_uint(f);
  return (u & 0x80000000u) ? ~u : (u | 0x80000000u);   // order-preserving map
}
__device__ __forceinline__ float key2f(u32 k){
  u32 u = (k & 0x80000000u) ? (k ^ 0x80000000u) : ~k;
  return __uint_as_float(u);
}
__device__ __forceinline__ u64 efix(float e){
  return (u64)((double)e * FIXS);   // e in [0,1]; exact in double, truncate
}

// JAX threefry2x32 with key (0,42)  (jax.random.key(42))
__device__ __forceinline__ void tf2x32(u32 x0, u32 x1, u32 &o0, u32 &o1){
  const u32 k0 = 0u, k1 = 42u, k2 = 0u ^ 42u ^ 0x1BD11BDAu;
  x0 += k0; x1 += k1;
#define TFR(r) { x0 += x1; x1 = (x1 << (r)) | (x1 >> (32 - (r))); x1 ^= x0; }
  TFR(13) TFR(15) TFR(26) TFR(6)
  x0 += k1; x1 += k2 + 1u;
  TFR(17) TFR(29) TFR(16) TFR(24)
  x0 += k2; x1 += k0 + 2u;
  TFR(13) TFR(15) TFR(26) TFR(6)
  x0 += k0; x1 += k1 + 3u;
  TFR(17) TFR(29) TFR(16) TFR(24)
  x0 += k1; x1 += k2 + 4u;
  TFR(13) TFR(15) TFR(26) TFR(6)
  x0 += k2; x1 += k0 + 5u;
#undef TFR
  o0 = x0; o1 = x1;
}

// JAX partitionable threefry: element index i -> tf2x32(key,(0,i)); bits = o0^o1.
__device__ __forceinline__ u32 gumbel_bits(u32 i){
  u32 o0, o1; tf2x32(0u, i, o0, o1);
  return o0 ^ o1;
}

// bits -> jax.random.uniform(1e-10,1.0) -> gumbel (precise logf; rare path).
__device__ __forceinline__ float bits2gumbel(u32 b){
  float f = __uint_as_float(0x3F800000u | (b >> 9)) - 1.0f;  // [0,1)
  float u = fmaxf(1e-10f, f + 1e-10f);
  return -logf(-logf(u));
}

// inclusive scans over NB entries in LDS (deterministic)
__device__ void scan_incl_u32(u32* a, u32* aux, int t){
  int base = t * 4;
  u32 x0=a[base], x1=a[base+1], x2=a[base+2], x3=a[base+3];
  x1 += x0; x2 += x1; x3 += x2;
  a[base]=x0; a[base+1]=x1; a[base+2]=x2; a[base+3]=x3;
  aux[t] = x3;
  __syncthreads();
  for (int off=1; off<BLK; off<<=1){
    u32 add = (t >= off) ? aux[t-off] : 0u;
    __syncthreads();
    aux[t] += add;
    __syncthreads();
  }
  u32 ex = t ? aux[t-1] : 0u;
  a[base]+=ex; a[base+1]+=ex; a[base+2]+=ex; a[base+3]+=ex;
  __syncthreads();
}
__device__ void scan_incl_u64(u64* a, u64* aux, int t){
  int base = t * 4;
  u64 x0=a[base], x1=a[base+1], x2=a[base+2], x3=a[base+3];
  x1 += x0; x2 += x1; x3 += x2;
  a[base]=x0; a[base+1]=x1; a[base+2]=x2; a[base+3]=x3;
  aux[t] = x3;
  __syncthreads();
  for (int off=1; off<BLK; off<<=1){
    u64 add = (t >= off) ? aux[t-off] : 0ULL;
    __syncthreads();
    aux[t] += add;
    __syncthreads();
  }
  u64 ex = t ? aux[t-1] : 0ULL;
  a[base]+=ex; a[base+1]+=ex; a[base+2]+=ex; a[base+3]+=ex;
  __syncthreads();
}

// ---------- kernel 1: stats + raw-key 3-level radix select ----------
__global__ __launch_bounds__(BLK) void k_prep(
    const float* __restrict__ logits, const float* __restrict__ temp,
    const float* __restrict__ minp, const int* __restrict__ topk,
    const float* __restrict__ topp,
    float* __restrict__ wst, int* __restrict__ wsg)
{
  __shared__ u32 cnt[NB];
  __shared__ u64 mass[NB];
  __shared__ u32 aux32[BLK];
  __shared__ u64 aux64[BLK];
  __shared__ float redv[BLK]; __shared__ u32 redi[BLK];
  __shared__ float redm[BLK]; __shared__ float redS[BLK];
  __shared__ float sh_m, sh_Z;
  __shared__ u32 sh_lstar;
  __shared__ u32 sh_b1k, sh_b1p, sh_b2k, sh_b2p, sh_b3k, sh_b3p, sh_r1, sh_r2;
  __shared__ u32 sh_kval;
  __shared__ u64 sh_t1, sh_t2, sh_tfix;

  const int b = blockIdx.x;
  const int t = threadIdx.x;
  const float T = temp[b];
  const bool greedy = (T < SEPS);
  const float invT = greedy ? 1.0f : (1.0f / T);
  const float* row = logits + (size_t)b * VOCAB;
  const float4* row4 = (const float4*)row;

  // ---- pass 1: raw max+argmax, online Z of s=l*invT, full count hist (raw keys) ----
  for (int i=t;i<NB;i+=BLK) cnt[i]=0u;
  __syncthreads();
  float M = -INFINITY; u32 Mi = 0u;
  float ms = -INFINITY, S = 0.0f;
  for (int i=t; i<NV4; i+=BLK){
    float4 q = row4[i];
    float vv[4] = {q.x,q.y,q.z,q.w};
    #pragma unroll
    for (int j=0;j<4;j++){
      float l = vv[j];
      u32 gi = (u32)(i*4+j);
      if (l > M){ M = l; Mi = gi; }
      float s = l * invT;
      if (s > ms){ S = S*__expf(ms - s) + 1.0f; ms = s; }
      else       { S += __expf(s - ms); }
      atomicAdd(&cnt[f2key(l)>>20], 1u);
    }
  }
  redv[t]=M; redi[t]=Mi; redm[t]=ms; redS[t]=S;
  __syncthreads();
  for (int off=BLK>>1; off>0; off>>=1){
    if (t < off){
      float M2=redv[t+off]; u32 I2=redi[t+off];
      if (M2 > redv[t] || (M2 == redv[t] && I2 < redi[t])){ redv[t]=M2; redi[t]=I2; }
      float m1=redm[t], S1=redS[t];
      float m2=redm[t+off], S2=redS[t+off];
      float mm = fmaxf(m1,m2);
      redS[t] = S1*__expf(m1-mm) + S2*__expf(m2-mm);
      redm[t] = mm;
    }
    __syncthreads();
  }
  if (t==0){
    sh_m = redm[0]; sh_Z = redS[0];
    wsg[b] = (int)redi[0];
    if (greedy) wst[b] = INFINITY;
    sh_b1k=0u; sh_b1p=0u; sh_b2k=0u; sh_b2p=0u; sh_b3k=0u; sh_b3p=0u;
    sh_r1=1u; sh_r2=1u; sh_t1=0ULL; sh_t2=0ULL;
  }
  __syncthreads();
  if (greedy) return;
  const float m = sh_m, Z = sh_Z;

  // ---- count scan + level-1 k crossing (rank over ALL tokens: tk-th largest) ----
  scan_incl_u32(cnt, aux32, t);
  int tk = topk[b]; if (tk < 1) tk = 1; if (tk > VOCAB) tk = VOCAB;
  const u32 R_all = (u32)(VOCAB - tk + 1);     // ascending rank of tk-th largest
  for (int i=t;i<NB;i+=BLK){
    if (cnt[i] >= R_all && (i?cnt[i-1]:0u) < R_all) sh_b1k = (u32)i;
  }
  __syncthreads();
  if (t==0){
    sh_r1 = R_all - (sh_b1k ? cnt[sh_b1k-1] : 0u);
    // ---- binary-search min-p raw cutoff l*: minimal key passing fl(e/Z) >= rhs
    float rhs = minp[b] * (1.0f / Z);
    u32 lo = 0u, hi = 0xFF800000u;             // hi = key(+inf), predicate true there
    while (lo < hi){
      u32 mid = lo + ((hi - lo) >> 1);
      float l = key2f(mid);
      float e = __expf(l * invT - m);
      if ((e / Z) >= rhs) hi = mid; else lo = mid + 1u;
    }
    sh_lstar = lo;
  }
  __syncthreads();
  const u32 b1k = sh_b1k, r1k_save = sh_r1, lstar = sh_lstar;

  // ---- pass 2: level-1 mass hist over kept (key>=lstar) + kept count K ----
  for (int i=t;i<NB;i+=BLK) mass[i]=0ULL;
  __syncthreads();
  u32 kcnt = 0u;
  for (int i=t; i<NV4; i+=BLK){
    float4 q = row4[i];
    float vv[4]={q.x,q.y,q.z,q.w};
    #pragma unroll
    for (int j=0;j<4;j++){
      float l = vv[j];
      u32 key = f2key(l);
      if (key >= lstar){
        kcnt++;
        float e = __expf(l * invT - m);
        atomicAdd(&mass[key>>20], efix(e));
      }
    }
  }
  redi[t] = kcnt;
  __syncthreads();
  for (int off=BLK>>1; off>0; off>>=1){
    if (t < off) redi[t] += redi[t+off];
    __syncthreads();
  }
  if (t==0) sh_kval = (redi[0] >= (u32)tk) ? 1u : 0u;
  __syncthreads();
  scan_incl_u64(mass, aux64, t);
  if (t==0){
    u64 Mtot = mass[NB-1];
    sh_tfix = (u64)((double)(1.0f - topp[b]) * (double)Mtot);
  }
  __syncthreads();
  const u64 tfix = sh_tfix;
  for (int i=t;i<NB;i+=BLK){
    if (mass[i] > tfix && (i?mass[i-1]:0ULL) <= tfix) sh_b1p = (u32)i;
  }
  __syncthreads();
  if (t==0) sh_t1 = tfix - (sh_b1p ? mass[sh_b1p-1] : 0ULL);
  __syncthreads();
  const u32 b1p = sh_b1p; const u64 t1 = sh_t1; const u32 r1 = r1k_save;
  const u32 kval = sh_kval;

  // ---- pass 3: level-2 hists (bits 19..8) within b1k / b1p ----
  __syncthreads();
  for (int i=t;i<NB;i+=BLK){ cnt[i]=0u; mass[i]=0ULL; }
  __syncthreads();
  for (int i=t; i<NV4; i+=BLK){
    float4 q = row4[i];
    float vv[4]={q.x,q.y,q.z,q.w};
    #pragma unroll
    for (int j=0;j<4;j++){
      float l = vv[j];
      u32 key = f2key(l);
      u32 hi = key >> 20;
      if (hi == b1k) atomicAdd(&cnt[(key>>8)&0xFFFu], 1u);
      if (hi == b1p && key >= lstar){
        float e = __expf(l * invT - m);
        atomicAdd(&mass[(key>>8)&0xFFFu], efix(e));
      }
    }
  }
  __syncthreads();
  scan_incl_u32(cnt, aux32, t);
  scan_incl_u64(mass, aux64, t);
  for (int i=t;i<NB;i+=BLK){
    if (cnt[i] >= r1 && (i?cnt[i-1]:0u) < r1)     sh_b2k = (u32)i;
    if (mass[i] > t1 && (i?mass[i-1]:0ULL) <= t1) sh_b2p = (u32)i;
  }
  __syncthreads();
  if (t==0){
    sh_r2 = r1 - (sh_b2k ? cnt[sh_b2k-1] : 0u);
    sh_t2 = t1 - (sh_b2p ? mass[sh_b2p-1] : 0ULL);
  }
  __syncthreads();
  const u32 b2k = sh_b2k, b2p = sh_b2p, r2 = sh_r2; const u64 t2 = sh_t2;
  const u32 prefk = (b1k << 12) | b2k;   // 24-bit prefix
  const u32 prefp = (b1p << 12) | b2p;

  // ---- pass 4: level-3 hists (low 8 bits) -> exact raw threshold keys ----
  __syncthreads();
  for (int i=t;i<256;i+=BLK){ cnt[i]=0u; mass[i]=0ULL; }
  __syncthreads();
  for (int i=t; i<NV4; i+=BLK){
    float4 q = row4[i];
    float vv[4]={q.x,q.y,q.z,q.w};
    #pragma unroll
    for (int j=0;j<4;j++){
      float l = vv[j];
      u32 key = f2key(l);
      u32 top = key >> 8;
      if (top == prefk) atomicAdd(&cnt[key & 0xFFu], 1u);
      if (top == prefp && key >= lstar){
        float e = __expf(l * invT - m);
        atomicAdd(&mass[key & 0xFFu], efix(e));
      }
    }
  }
  __syncthreads();
  for (int off=1; off<256; off<<=1){
    u32 ca = 0u; u64 ma = 0ULL;
    if (t < 256 && t >= off){ ca = cnt[t-off]; ma = mass[t-off]; }
    __syncthreads();
    if (t < 256 && t >= off){ cnt[t] += ca; mass[t] += ma; }
    __syncthreads();
  }
  if (t < 256){
    if (cnt[t] >= r2 && (t==0 || cnt[t-1] < r2))   sh_b3k = (u32)t;
    if (mass[t] > t2 && (t==0 || mass[t-1] <= t2)) sh_b3p = (u32)t;
  }
  __syncthreads();
  if (t==0){
    u32 kkey = kval ? ((prefk << 8) | sh_b3k) : 0u;   // 0 => effectively -inf
    u32 pkey = (prefp << 8) | sh_b3p;
    u32 thr  = (kkey > pkey) ? kkey : pkey;
    wst[b] = key2f(thr);                 // raw-logit threshold (min-p implied)
  }
}

// ---------- kernel 2: gumbel-max over survivors (<= ~63 per row) ----------
__global__ __launch_bounds__(BLK) void k_sample(
    const float* __restrict__ logits, const float* __restrict__ temp,
    const float* __restrict__ wst, const int* __restrict__ wsg,
    int* __restrict__ out)
{
  const int r = blockIdx.x;
  const int t = threadIdx.x;
  __shared__ float rv[BLK]; __shared__ u32 ri[BLK];
  const float T = temp[r];
  if (T < SEPS){ if (t==0) out[r] = wsg[r]; return; }
  const float invT = 1.0f / T;
  const float thr = wst[r];
  const float* row = logits + (size_t)r * VOCAB;
  const float4* row4 = (const float4*)row;
  float best=-INFINITY; u32 bi=0xFFFFFFFFu;

  for (int i=t; i<NV4; i+=BLK){
    float4 q = row4[i];
    float vv[4]={q.x,q.y,q.z,q.w};
    #pragma unroll
    for (int j=0;j<4;j++){
      float l = vv[j];
      if (l >= thr){                         // rare (<= ~63 per row)
        u32 idx = (u32)(i*4+j);
        u32 c = (u32)r * (u32)VOCAB + idx;   // linear element index (< 2^32)
        float cand = l * invT + bits2gumbel(gumbel_bits(c));
        if (cand > best || (cand == best && idx < bi)){ best=cand; bi=idx; }
      }
    }
  }
  rv[t]=best; ri[t]=bi;
  __syncthreads();
  for (int off=BLK>>1; off>0; off>>=1){
    if (t < off){
      if (rv[t+off] > rv[t] || (rv[t+off]==rv[t] && ri[t+off] < ri[t])){
        rv[t]=rv[t+off]; ri[t]=ri[t+off];
      }
    }
    __syncthreads();
  }
  if (t==0) out[r] = (int)ri[0];
}

extern "C" void kernel_launch(void* const* d_in, const int* in_sizes, int n_in,
                              void* d_out, int out_size, void* d_ws, size_t ws_size,
                              hipStream_t stream)
{
  const float* logits = (const float*)d_in[0];
  const float* temp   = (const float*)d_in[1];
  const float* minp   = (const float*)d_in[2];
  const int*   topk   = (const int*)d_in[3];
  const float* topp   = (const float*)d_in[4];

  char* ws = (char*)d_ws;
  float* wst = (float*)(ws + 0);       // [256] raw-logit threshold
  int*   wsg = (int*)(ws + 1024);      // [256] greedy argmax

  int* out = (int*)d_out;

  hipLaunchKernelGGL(k_prep,   dim3(NROWS), dim3(BLK), 0, stream,
                     logits, temp, minp, topk, topp, wst, wsg);
  hipLaunchKernelGGL(k_sample, dim3(NROWS), dim3(BLK), 0, stream,
                     logits, temp, wst, wsg, out);
}

// Round 4
// 106.338 us; speedup vs baseline: 1.9223x; 1.2950x over previous
//
#include <hip/hip_runtime.h>
#include <stdint.h>

typedef unsigned long long u64;
typedef unsigned int u32;

#define VOCAB 128000
#define NV4   32000      // VOCAB/4
#define NROWS 256
#define BLK   1024
#define NW    16         // waves per block
#define NB    4096
#define CAPA  4096       // top-k boundary-bucket list (tail bucket: tiny in practice)
#define CAPB  8192       // top-p boundary-bucket list (bulk bucket: <=~3000 typ.)
#define SEPS  1e-5f
#define FIXS  17592186044416.0  /* 2^44 fixed-point scale */

// ---------- helpers ----------
__device__ __forceinline__ u32 f2key(float f){
  u32 u = __float_as_uint(f);
  return (u & 0x80000000u) ? ~u : (u | 0x80000000u);   // order-preserving
}
__device__ __forceinline__ float key2f(u32 k){
  u32 u = (k & 0x80000000u) ? (k ^ 0x80000000u) : ~k;
  return __uint_as_float(u);
}
__device__ __forceinline__ u64 efix(float e){
  return (u64)((double)e * FIXS);
}

// JAX threefry2x32, key (0,42)
__device__ __forceinline__ void tf2x32(u32 x0, u32 x1, u32 &o0, u32 &o1){
  const u32 k0 = 0u, k1 = 42u, k2 = 0u ^ 42u ^ 0x1BD11BDAu;
  x0 += k0; x1 += k1;
#define TFR(r) { x0 += x1; x1 = (x1 << (r)) | (x1 >> (32 - (r))); x1 ^= x0; }
  TFR(13) TFR(15) TFR(26) TFR(6)
  x0 += k1; x1 += k2 + 1u;
  TFR(17) TFR(29) TFR(16) TFR(24)
  x0 += k2; x1 += k0 + 2u;
  TFR(13) TFR(15) TFR(26) TFR(6)
  x0 += k0; x1 += k1 + 3u;
  TFR(17) TFR(29) TFR(16) TFR(24)
  x0 += k1; x1 += k2 + 4u;
  TFR(13) TFR(15) TFR(26) TFR(6)
  x0 += k2; x1 += k0 + 5u;
#undef TFR
  o0 = x0; o1 = x1;
}
// partitionable threefry: elem index i -> tf2x32(key,(0,i)); bits = o0^o1
__device__ __forceinline__ u32 gumbel_bits(u32 i){
  u32 o0, o1; tf2x32(0u, i, o0, o1);
  return o0 ^ o1;
}
__device__ __forceinline__ float bits2gumbel(u32 b){
  float f = __uint_as_float(0x3F800000u | (b >> 9)) - 1.0f;  // [0,1)
  float u = fmaxf(1e-10f, f + 1e-10f);
  return -logf(-logf(u));
}

// ---------- crossing searches (reduce + wave-0 descent; NO block scans) ----------
// find first idx with inclusive-cum(arr) > target. caller: __syncthreads()
// BEFORE (data ready) and AFTER (results visible).
__device__ __forceinline__ void cross4096_u32(
    const u32* arr, u32* aux, u32 target, u32* out_idx, u32* out_before, int t)
{
  aux[t] = arr[4*t+0] + arr[4*t+1] + arr[4*t+2] + arr[4*t+3];
  __syncthreads();
  if (t < 64){
    u32 gs = 0u;
    #pragma unroll
    for (int j=0;j<16;j++) gs += aux[t*16+j];
    u32 pref = gs;
    #pragma unroll
    for (int d=1; d<64; d<<=1){ u32 v = __shfl_up(pref, d, 64); if (t >= d) pref += v; }
    u64 bal = __ballot(pref > target);
    int g = bal ? (__ffsll((long long)bal) - 1) : 63;
    u32 pg = __shfl(pref, g, 64);
    u32 gg = __shfl(gs, g, 64);
    if (t == 0){
      u32 c = pg - gg;
      u32 idx = (u32)(g*64 + 63);
      for (int j=0;j<16;j++){
        u32 v = aux[g*16+j];
        if (c + v > target){
          int base = (g*16+j)*4;
          for (int q=0;q<4;q++){
            u32 w = arr[base+q];
            if (c + w > target){ idx = (u32)(base+q); goto doneu; }
            c += w;
          }
        }
        c += v;
      }
      doneu:
      *out_idx = idx; *out_before = c;
    }
  }
}

__device__ __forceinline__ void cross4096_u64(
    const u64* arr, u64* aux, u64 target, u32* out_idx, u64* out_before, int t)
{
  aux[t] = arr[4*t+0] + arr[4*t+1] + arr[4*t+2] + arr[4*t+3];
  __syncthreads();
  if (t < 64){
    u64 gs = 0ull;
    #pragma unroll
    for (int j=0;j<16;j++) gs += aux[t*16+j];
    u64 pref = gs;
    #pragma unroll
    for (int d=1; d<64; d<<=1){
      u64 v = __shfl_up((unsigned long long)pref, d, 64); if (t >= d) pref += v;
    }
    u64 bal = __ballot(pref > target);
    int g = bal ? (__ffsll((long long)bal) - 1) : 63;
    u64 pg = __shfl((unsigned long long)pref, g, 64);
    u64 gg = __shfl((unsigned long long)gs, g, 64);
    if (t == 0){
      u64 c = pg - gg;
      u32 idx = (u32)(g*64 + 63);
      for (int j=0;j<16;j++){
        u64 v = aux[g*16+j];
        if (c + v > target){
          int base = (g*16+j)*4;
          for (int q=0;q<4;q++){
            u64 w = arr[base+q];
            if (c + w > target){ idx = (u32)(base+q); goto donev; }
            c += w;
          }
        }
        c += v;
      }
      donev:
      *out_idx = idx; *out_before = c;
    }
  }
}

// level-1 mass: also derives total and target = (1-topp)*total
__device__ __forceinline__ void cross4096_mass(
    const u64* arr, u64* aux, float topp_v, u64* out_target,
    u32* out_idx, u64* out_before, int t)
{
  aux[t] = arr[4*t+0] + arr[4*t+1] + arr[4*t+2] + arr[4*t+3];
  __syncthreads();
  if (t < 64){
    u64 gs = 0ull;
    #pragma unroll
    for (int j=0;j<16;j++) gs += aux[t*16+j];
    u64 pref = gs;
    #pragma unroll
    for (int d=1; d<64; d<<=1){
      u64 v = __shfl_up((unsigned long long)pref, d, 64); if (t >= d) pref += v;
    }
    u64 total = __shfl((unsigned long long)pref, 63, 64);
    u64 target = (u64)((double)(1.0f - topp_v) * (double)total);
    u64 bal = __ballot(pref > target);
    int g = bal ? (__ffsll((long long)bal) - 1) : 63;
    u64 pg = __shfl((unsigned long long)pref, g, 64);
    u64 gg = __shfl((unsigned long long)gs, g, 64);
    if (t == 0){
      u64 c = pg - gg;
      u32 idx = (u32)(g*64 + 63);
      for (int j=0;j<16;j++){
        u64 v = aux[g*16+j];
        if (c + v > target){
          int base = (g*16+j)*4;
          for (int q=0;q<4;q++){
            u64 w = arr[base+q];
            if (c + w > target){ idx = (u32)(base+q); goto donem; }
            c += w;
          }
        }
        c += v;
      }
      donem:
      *out_target = target; *out_idx = idx; *out_before = c;
    }
  }
}

__device__ __forceinline__ void cross256_u32(const u32* arr, u32 target, u32* out_idx, int t){
  if (t < 64){
    u32 gs = arr[4*t+0]+arr[4*t+1]+arr[4*t+2]+arr[4*t+3];
    u32 pref = gs;
    #pragma unroll
    for (int d=1; d<64; d<<=1){ u32 v=__shfl_up(pref,d,64); if (t>=d) pref+=v; }
    u64 bal = __ballot(pref > target);
    int g = bal ? (__ffsll((long long)bal)-1) : 63;
    u32 pg=__shfl(pref,g,64), gg=__shfl(gs,g,64);
    if (t==0){
      u32 c = pg-gg; u32 idx=(u32)(g*4+3);
      for (int q=0;q<4;q++){ u32 w=arr[g*4+q]; if (c+w>target){ idx=(u32)(g*4+q); break; } c+=w; }
      *out_idx = idx;
    }
  }
}
__device__ __forceinline__ void cross256_u64(const u64* arr, u64 target, u32* out_idx, int t){
  if (t < 64){
    u64 gs = arr[4*t+0]+arr[4*t+1]+arr[4*t+2]+arr[4*t+3];
    u64 pref = gs;
    #pragma unroll
    for (int d=1; d<64; d<<=1){
      u64 v=__shfl_up((unsigned long long)pref,d,64); if (t>=d) pref+=v;
    }
    u64 bal = __ballot(pref > target);
    int g = bal ? (__ffsll((long long)bal)-1) : 63;
    u64 pg=__shfl((unsigned long long)pref,g,64), gg=__shfl((unsigned long long)gs,g,64);
    if (t==0){
      u64 c = pg-gg; u32 idx=(u32)(g*4+3);
      for (int q=0;q<4;q++){ u64 w=arr[g*4+q]; if (c+w>target){ idx=(u32)(g*4+q); break; } c+=w; }
      *out_idx = idx;
    }
  }
}

// safe (m,S) logsumexp merge (handles -inf neutrals without NaN)
__device__ __forceinline__ void msmerge(float &m1, float &S1, float m2, float S2){
  float mm = fmaxf(m1, m2);
  if (mm == -INFINITY){ m1 = mm; S1 = 0.0f; return; }
  S1 = S1*__expf(m1-mm) + S2*__expf(m2-mm);
  m1 = mm;
}

// ---------- the fused kernel: one block per row ----------
__global__ __launch_bounds__(BLK) void k_all(
    const float* __restrict__ logits, const float* __restrict__ temp,
    const float* __restrict__ minp, const int* __restrict__ topk,
    const float* __restrict__ topp, int* __restrict__ out)
{
  __shared__ u32 cnt[NB];          // 16KB
  __shared__ u64 mass[NB];         // 32KB
  __shared__ u32 aux32[BLK];       // 4KB
  __shared__ u64 aux64[BLK];       // 8KB
  __shared__ u32 listA[CAPA];      // 16KB
  __shared__ u32 listB[CAPB];      // 32KB
  __shared__ float wrf1[NW], wrf2[NW];
  __shared__ u32  wru1[NW];
  __shared__ float sh_m, sh_Z, sh_thr;
  __shared__ u32 sh_lstar, sh_K, sh_lenA, sh_lenB;
  __shared__ u32 sh_idx; __shared__ u32 sh_bef32;
  __shared__ u64 sh_bef64, sh_tfix;

  const int b = blockIdx.x;
  const int t = threadIdx.x;
  const int ln = t & 63, wv = t >> 6;
  const float T = temp[b];
  const float* row = logits + (size_t)b * VOCAB;
  const float4* row4 = (const float4*)row;

  // ======== greedy rows: argmax only ========
  if (T < SEPS){
    float M = -INFINITY; u32 Mi = 0xFFFFFFFFu;
    for (int i=t; i<NV4; i+=BLK){
      float4 q = row4[i];
      float vv[4] = {q.x,q.y,q.z,q.w};
      #pragma unroll
      for (int j=0;j<4;j++){
        float l = vv[j]; u32 gi = (u32)(i*4+j);
        if (l > M){ M = l; Mi = gi; }
      }
    }
    #pragma unroll
    for (int d=32; d>0; d>>=1){
      float M2 = __shfl_down(M, d, 64); u32 I2 = __shfl_down(Mi, d, 64);
      if (M2 > M || (M2 == M && I2 < Mi)){ M = M2; Mi = I2; }
    }
    if (ln==0){ wrf1[wv]=M; wru1[wv]=Mi; }
    __syncthreads();
    if (wv==0){
      float M1 = (ln<NW)? wrf1[ln] : -INFINITY;
      u32 I1 = (ln<NW)? wru1[ln] : 0xFFFFFFFFu;
      #pragma unroll
      for (int d=32; d>0; d>>=1){
        float M2 = __shfl_down(M1, d, 64); u32 I2 = __shfl_down(I1, d, 64);
        if (M2 > M1 || (M2 == M1 && I2 < I1)){ M1 = M2; I1 = I2; }
      }
      if (ln==0) out[b] = (int)I1;
    }
    return;
  }

  // ======== P1: online (m,Z) of s=l*invT + 12-bit count hist of raw keys ========
  const float invT = 1.0f / T;
  for (int i=t;i<NB;i+=BLK) cnt[i]=0u;
  __syncthreads();
  float ms = -INFINITY, S = 0.0f;
  for (int i=t; i<NV4; i+=BLK){
    float4 q = row4[i];
    float vv[4] = {q.x,q.y,q.z,q.w};
    #pragma unroll
    for (int j=0;j<4;j++){
      float l = vv[j];
      float s = l * invT;
      if (s > ms){ S = S*__expf(ms - s) + 1.0f; ms = s; }
      else       { S += __expf(s - ms); }
      atomicAdd(&cnt[f2key(l)>>20], 1u);
    }
  }
  #pragma unroll
  for (int d=32; d>0; d>>=1){
    float m2 = __shfl_down(ms, d, 64); float S2 = __shfl_down(S, d, 64);
    msmerge(ms, S, m2, S2);
  }
  if (ln==0){ wrf1[wv]=ms; wrf2[wv]=S; }
  __syncthreads();
  if (wv==0){
    float m1 = (ln<NW)? wrf1[ln] : -INFINITY;
    float S1 = (ln<NW)? wrf2[ln] : 0.0f;
    #pragma unroll
    for (int d=32; d>0; d>>=1){
      float m2 = __shfl_down(m1, d, 64); float S2 = __shfl_down(S1, d, 64);
      msmerge(m1, S1, m2, S2);
    }
    if (ln==0){ sh_m = m1; sh_Z = S1; }
  }
  __syncthreads();
  const float m = sh_m, Z = sh_Z;

  // top-k level-1 crossing over full counts (rank over ALL tokens)
  int tk = topk[b]; if (tk < 1) tk = 1; if (tk > VOCAB) tk = VOCAB;
  cross4096_u32(cnt, aux32, (u32)(VOCAB - tk), &sh_idx, &sh_bef32, t); // target=R_all-1
  __syncthreads();
  const u32 b1k = sh_idx;
  const u32 r1  = (u32)(VOCAB - tk + 1) - sh_bef32;

  // min-p raw cutoff l*: minimal key with fl(e/Z) >= rhs (monotone predicate)
  if (t==0){
    float rhs = minp[b] * (1.0f / Z);
    u32 lo = 0u, hi = 0xFF800000u;   // key(+inf)
    while (lo < hi){
      u32 mid = lo + ((hi - lo) >> 1);
      float e = __expf(key2f(mid) * invT - m);
      if ((e / Z) >= rhs) hi = mid; else lo = mid + 1u;
    }
    sh_lstar = lo; sh_K = 0u; sh_lenA = 0u;
  }
  __syncthreads();
  const u32 lstar = sh_lstar;

  // ======== P2: kept-only 12-bit mass hist + compact top-k bucket (listA) ========
  for (int i=t;i<NB;i+=BLK) mass[i]=0ull;
  __syncthreads();
  u32 kc = 0u;
  for (int i=t; i<NV4; i+=BLK){
    float4 q = row4[i];
    float vv[4] = {q.x,q.y,q.z,q.w};
    #pragma unroll
    for (int j=0;j<4;j++){
      float l = vv[j];
      u32 key = f2key(l);
      if (key >= lstar){
        kc++;
        atomicAdd(&mass[key>>20], efix(__expf(l*invT - m)));
      }
      if ((key>>20) == b1k){
        u32 p = atomicAdd(&sh_lenA, 1u);
        if (p < CAPA) listA[p] = key;
      }
    }
  }
  #pragma unroll
  for (int d=32; d>0; d>>=1) kc += __shfl_down(kc, d, 64);
  if (ln==0) atomicAdd(&sh_K, kc);
  __syncthreads();
  cross4096_mass(mass, aux64, topp[b], &sh_tfix, &sh_idx, &sh_bef64, t);
  __syncthreads();
  const u32 b1p = sh_idx;
  const u64 t1  = sh_tfix - sh_bef64;
  const u32 kval = (sh_K >= (u32)tk) ? 1u : 0u;
  const u32 lenA = sh_lenA;                 // exact count of bucket b1k
  const u32 lenBbound = cnt[b1p];           // bound on filtered bucket count
  const bool fast = ((!kval || lenA <= CAPA) && (lenBbound <= CAPB));

  u32 kkey = 0u, pkey = 0u;

  if (fast){
    // ---- P3: compact top-p boundary bucket (kept tokens only) ----
    if (t==0) sh_lenB = 0u;
    __syncthreads();
    for (int i=t; i<NV4; i+=BLK){
      float4 q = row4[i];
      float vv[4] = {q.x,q.y,q.z,q.w};
      #pragma unroll
      for (int j=0;j<4;j++){
        u32 key = f2key(vv[j]);
        if ((key>>20) == b1p && key >= lstar){
          u32 p = atomicAdd(&sh_lenB, 1u);
          listB[p] = key;
        }
      }
    }
    __syncthreads();
    const u32 lenB = sh_lenB;

    // ---- refine A in-LDS (bits 19..8 then 7..0) ----
    if (kval){
      for (int i=t;i<NB;i+=BLK) cnt[i]=0u;
      __syncthreads();
      for (u32 i=t; i<lenA; i+=BLK) atomicAdd(&cnt[(listA[i]>>8)&0xFFFu], 1u);
      __syncthreads();
      cross4096_u32(cnt, aux32, r1-1u, &sh_idx, &sh_bef32, t);
      __syncthreads();
      u32 b2k = sh_idx; u32 r2 = r1 - sh_bef32;
      for (int i=t;i<256;i+=BLK) cnt[i]=0u;
      __syncthreads();
      for (u32 i=t; i<lenA; i+=BLK){
        u32 key = listA[i];
        if (((key>>8)&0xFFFu) == b2k) atomicAdd(&cnt[key&0xFFu], 1u);
      }
      __syncthreads();
      cross256_u32(cnt, r2-1u, &sh_idx, t);
      __syncthreads();
      kkey = (b1k<<20) | (b2k<<8) | sh_idx;
    }
    // ---- refine B in-LDS ----
    for (int i=t;i<NB;i+=BLK) mass[i]=0ull;
    __syncthreads();
    for (u32 i=t; i<lenB; i+=BLK){
      u32 key = listB[i];
      atomicAdd(&mass[(key>>8)&0xFFFu], efix(__expf(key2f(key)*invT - m)));
    }
    __syncthreads();
    cross4096_u64(mass, aux64, t1, &sh_idx, &sh_bef64, t);
    __syncthreads();
    u32 b2p = sh_idx; u64 t2 = t1 - sh_bef64;
    for (int i=t;i<256;i+=BLK) mass[i]=0ull;
    __syncthreads();
    for (u32 i=t; i<lenB; i+=BLK){
      u32 key = listB[i];
      if (((key>>8)&0xFFFu) == b2p) atomicAdd(&mass[key&0xFFu], efix(__expf(key2f(key)*invT - m)));
    }
    __syncthreads();
    cross256_u64(mass, t2, &sh_idx, t);
    __syncthreads();
    pkey = (b1p<<20) | (b2p<<8) | sh_idx;
  } else {
    // ---- slow path: global re-stream level-2 then level-3 (always correct) ----
    for (int i=t;i<NB;i+=BLK){ cnt[i]=0u; mass[i]=0ull; }
    __syncthreads();
    for (int i=t; i<NV4; i+=BLK){
      float4 q = row4[i];
      float vv[4] = {q.x,q.y,q.z,q.w};
      #pragma unroll
      for (int j=0;j<4;j++){
        float l = vv[j]; u32 key = f2key(l); u32 hi = key>>20;
        if (kval && hi == b1k) atomicAdd(&cnt[(key>>8)&0xFFFu], 1u);
        if (hi == b1p && key >= lstar)
          atomicAdd(&mass[(key>>8)&0xFFFu], efix(__expf(l*invT - m)));
      }
    }
    __syncthreads();
    cross4096_u32(cnt, aux32, r1-1u, &sh_idx, &sh_bef32, t);
    __syncthreads();
    u32 b2k = sh_idx; u32 r2 = r1 - sh_bef32;
    cross4096_u64(mass, aux64, t1, &sh_idx, &sh_bef64, t);
    __syncthreads();
    u32 b2p = sh_idx; u64 t2 = t1 - sh_bef64;
    for (int i=t;i<256;i+=BLK){ cnt[i]=0u; mass[i]=0ull; }
    __syncthreads();
    for (int i=t; i<NV4; i+=BLK){
      float4 q = row4[i];
      float vv[4] = {q.x,q.y,q.z,q.w};
      #pragma unroll
      for (int j=0;j<4;j++){
        float l = vv[j]; u32 key = f2key(l);
        if (kval && (key>>20)==b1k && ((key>>8)&0xFFFu)==b2k)
          atomicAdd(&cnt[key&0xFFu], 1u);
        if ((key>>20)==b1p && ((key>>8)&0xFFFu)==b2p && key >= lstar)
          atomicAdd(&mass[key&0xFFu], efix(__expf(l*invT - m)));
      }
    }
    __syncthreads();
    cross256_u32(cnt, r2-1u, &sh_idx, t);
    __syncthreads();
    if (kval) kkey = (b1k<<20) | (b2k<<8) | sh_idx;
    cross256_u64(mass, t2, &sh_idx, t);
    __syncthreads();
    pkey = (b1p<<20) | (b2p<<8) | sh_idx;
  }
  if (t==0) sh_thr = key2f(kkey > pkey ? kkey : pkey);
  __syncthreads();

  // ======== P4: gumbel-max over survivors (<= ~63 per row) ========
  const float thr = sh_thr;
  float best = -INFINITY; u32 bi = 0xFFFFFFFFu;
  for (int i=t; i<NV4; i+=BLK){
    float4 q = row4[i];
    float vv[4] = {q.x,q.y,q.z,q.w};
    #pragma unroll
    for (int j=0;j<4;j++){
      float l = vv[j];
      if (l >= thr){
        u32 idx = (u32)(i*4+j);
        u32 c = (u32)b * (u32)VOCAB + idx;
        float cand = l * invT + bits2gumbel(gumbel_bits(c));
        if (cand > best || (cand == best && idx < bi)){ best = cand; bi = idx; }
      }
    }
  }
  #pragma unroll
  for (int d=32; d>0; d>>=1){
    float c2 = __shfl_down(best, d, 64); u32 i2 = __shfl_down(bi, d, 64);
    if (c2 > best || (c2 == best && i2 < bi)){ best = c2; bi = i2; }
  }
  if (ln==0){ wrf1[wv]=best; wru1[wv]=bi; }
  __syncthreads();
  if (wv==0){
    float b1 = (ln<NW)? wrf1[ln] : -INFINITY;
    u32 i1 = (ln<NW)? wru1[ln] : 0xFFFFFFFFu;
    #pragma unroll
    for (int d=32; d>0; d>>=1){
      float b2 = __shfl_down(b1, d, 64); u32 i2 = __shfl_down(i1, d, 64);
      if (b2 > b1 || (b2 == b1 && i2 < i1)){ b1 = b2; i1 = i2; }
    }
    if (ln==0) out[b] = (int)i1;
  }
}

extern "C" void kernel_launch(void* const* d_in, const int* in_sizes, int n_in,
                              void* d_out, int out_size, void* d_ws, size_t ws_size,
                              hipStream_t stream)
{
  const float* logits = (const float*)d_in[0];
  const float* temp   = (const float*)d_in[1];
  const float* minp   = (const float*)d_in[2];
  const int*   topk   = (const int*)d_in[3];
  const float* topp   = (const float*)d_in[4];
  int* out = (int*)d_out;

  hipLaunchKernelGGL(k_all, dim3(NROWS), dim3(BLK), 0, stream,
                     logits, temp, minp, topk, topp, out);
}

// Round 5
// 63.934 us; speedup vs baseline: 3.1973x; 1.6633x over previous
//
#include <hip/hip_runtime.h>
#include <stdint.h>

typedef unsigned long long u64;
typedef unsigned int u32;

#define VOCAB 128000
#define NV4   32000      // VOCAB/4
#define NROWS 256
#define BLK   1024
#define NW    16         // waves per block
#define NB    4096
#define CAPL  4096       // compacted candidate list capacity ((key,idx) pairs)
#define SEPS  1e-5f
#define FIXS  17592186044416.0  /* 2^44 fixed-point scale */

// ---------- helpers ----------
__device__ __forceinline__ u32 f2key(float f){
  u32 u = __float_as_uint(f);
  return (u & 0x80000000u) ? ~u : (u | 0x80000000u);   // order-preserving
}
__device__ __forceinline__ float key2f(u32 k){
  u32 u = (k & 0x80000000u) ? (k ^ 0x80000000u) : ~k;
  return __uint_as_float(u);
}
__device__ __forceinline__ u64 efix(float e){
  return (u64)((double)e * FIXS);
}

// JAX threefry2x32, key (0,42)
__device__ __forceinline__ void tf2x32(u32 x0, u32 x1, u32 &o0, u32 &o1){
  const u32 k0 = 0u, k1 = 42u, k2 = 0u ^ 42u ^ 0x1BD11BDAu;
  x0 += k0; x1 += k1;
#define TFR(r) { x0 += x1; x1 = (x1 << (r)) | (x1 >> (32 - (r))); x1 ^= x0; }
  TFR(13) TFR(15) TFR(26) TFR(6)
  x0 += k1; x1 += k2 + 1u;
  TFR(17) TFR(29) TFR(16) TFR(24)
  x0 += k2; x1 += k0 + 2u;
  TFR(13) TFR(15) TFR(26) TFR(6)
  x0 += k0; x1 += k1 + 3u;
  TFR(17) TFR(29) TFR(16) TFR(24)
  x0 += k1; x1 += k2 + 4u;
  TFR(13) TFR(15) TFR(26) TFR(6)
  x0 += k2; x1 += k0 + 5u;
#undef TFR
  o0 = x0; o1 = x1;
}
// partitionable threefry: elem index i -> tf2x32(key,(0,i)); bits = o0^o1
__device__ __forceinline__ u32 gumbel_bits(u32 i){
  u32 o0, o1; tf2x32(0u, i, o0, o1);
  return o0 ^ o1;
}
__device__ __forceinline__ float bits2gumbel(u32 b){
  float f = __uint_as_float(0x3F800000u | (b >> 9)) - 1.0f;  // [0,1)
  float u = fmaxf(1e-10f, f + 1e-10f);
  return -logf(-logf(u));
}

// ---------- crossing searches (reduce + wave-0 descent) ----------
// find first idx with inclusive-cum(arr) > target. caller barriers before+after.
__device__ __forceinline__ void cross4096_u32(
    const u32* arr, u32* aux, u32 target, u32* out_idx, u32* out_before, int t)
{
  aux[t] = arr[4*t+0] + arr[4*t+1] + arr[4*t+2] + arr[4*t+3];
  __syncthreads();
  if (t < 64){
    u32 gs = 0u;
    #pragma unroll
    for (int j=0;j<16;j++) gs += aux[t*16+j];
    u32 pref = gs;
    #pragma unroll
    for (int d=1; d<64; d<<=1){ u32 v = __shfl_up(pref, d, 64); if (t >= d) pref += v; }
    u64 bal = __ballot(pref > target);
    int g = bal ? (__ffsll((long long)bal) - 1) : 63;
    u32 pg = __shfl(pref, g, 64);
    u32 gg = __shfl(gs, g, 64);
    if (t == 0){
      u32 c = pg - gg;
      u32 idx = (u32)(g*64 + 63);
      for (int j=0;j<16;j++){
        u32 v = aux[g*16+j];
        if (c + v > target){
          int base = (g*16+j)*4;
          for (int q=0;q<4;q++){
            u32 w = arr[base+q];
            if (c + w > target){ idx = (u32)(base+q); goto doneu; }
            c += w;
          }
        }
        c += v;
      }
      doneu:
      *out_idx = idx; *out_before = c;
    }
  }
}

__device__ __forceinline__ void cross4096_u64(
    const u64* arr, u64* aux, u64 target, u32* out_idx, u64* out_before, int t)
{
  aux[t] = arr[4*t+0] + arr[4*t+1] + arr[4*t+2] + arr[4*t+3];
  __syncthreads();
  if (t < 64){
    u64 gs = 0ull;
    #pragma unroll
    for (int j=0;j<16;j++) gs += aux[t*16+j];
    u64 pref = gs;
    #pragma unroll
    for (int d=1; d<64; d<<=1){
      u64 v = __shfl_up((unsigned long long)pref, d, 64); if (t >= d) pref += v;
    }
    u64 bal = __ballot(pref > target);
    int g = bal ? (__ffsll((long long)bal) - 1) : 63;
    u64 pg = __shfl((unsigned long long)pref, g, 64);
    u64 gg = __shfl((unsigned long long)gs, g, 64);
    if (t == 0){
      u64 c = pg - gg;
      u32 idx = (u32)(g*64 + 63);
      for (int j=0;j<16;j++){
        u64 v = aux[g*16+j];
        if (c + v > target){
          int base = (g*16+j)*4;
          for (int q=0;q<4;q++){
            u64 w = arr[base+q];
            if (c + w > target){ idx = (u32)(base+q); goto donev; }
            c += w;
          }
        }
        c += v;
      }
      donev:
      *out_idx = idx; *out_before = c;
    }
  }
}

// level-1 mass: derives total and target = (1-topp)*total internally
__device__ __forceinline__ void cross4096_mass(
    const u64* arr, u64* aux, float topp_v, u64* out_target,
    u32* out_idx, u64* out_before, int t)
{
  aux[t] = arr[4*t+0] + arr[4*t+1] + arr[4*t+2] + arr[4*t+3];
  __syncthreads();
  if (t < 64){
    u64 gs = 0ull;
    #pragma unroll
    for (int j=0;j<16;j++) gs += aux[t*16+j];
    u64 pref = gs;
    #pragma unroll
    for (int d=1; d<64; d<<=1){
      u64 v = __shfl_up((unsigned long long)pref, d, 64); if (t >= d) pref += v;
    }
    u64 total = __shfl((unsigned long long)pref, 63, 64);
    u64 target = (u64)((double)(1.0f - topp_v) * (double)total);
    u64 bal = __ballot(pref > target);
    int g = bal ? (__ffsll((long long)bal) - 1) : 63;
    u64 pg = __shfl((unsigned long long)pref, g, 64);
    u64 gg = __shfl((unsigned long long)gs, g, 64);
    if (t == 0){
      u64 c = pg - gg;
      u32 idx = (u32)(g*64 + 63);
      for (int j=0;j<16;j++){
        u64 v = aux[g*16+j];
        if (c + v > target){
          int base = (g*16+j)*4;
          for (int q=0;q<4;q++){
            u64 w = arr[base+q];
            if (c + w > target){ idx = (u32)(base+q); goto donem; }
            c += w;
          }
        }
        c += v;
      }
      donem:
      *out_target = target; *out_idx = idx; *out_before = c;
    }
  }
}

__device__ __forceinline__ void cross256_u32(const u32* arr, u32 target, u32* out_idx, int t){
  if (t < 64){
    u32 gs = arr[4*t+0]+arr[4*t+1]+arr[4*t+2]+arr[4*t+3];
    u32 pref = gs;
    #pragma unroll
    for (int d=1; d<64; d<<=1){ u32 v=__shfl_up(pref,d,64); if (t>=d) pref+=v; }
    u64 bal = __ballot(pref > target);
    int g = bal ? (__ffsll((long long)bal)-1) : 63;
    u32 pg=__shfl(pref,g,64), gg=__shfl(gs,g,64);
    if (t==0){
      u32 c = pg-gg; u32 idx=(u32)(g*4+3);
      for (int q=0;q<4;q++){ u32 w=arr[g*4+q]; if (c+w>target){ idx=(u32)(g*4+q); break; } c+=w; }
      *out_idx = idx;
    }
  }
}
__device__ __forceinline__ void cross256_u64(const u64* arr, u64 target, u32* out_idx, int t){
  if (t < 64){
    u64 gs = arr[4*t+0]+arr[4*t+1]+arr[4*t+2]+arr[4*t+3];
    u64 pref = gs;
    #pragma unroll
    for (int d=1; d<64; d<<=1){
      u64 v=__shfl_up((unsigned long long)pref,d,64); if (t>=d) pref+=v;
    }
    u64 bal = __ballot(pref > target);
    int g = bal ? (__ffsll((long long)bal)-1) : 63;
    u64 pg=__shfl((unsigned long long)pref,g,64), gg=__shfl((unsigned long long)gs,g,64);
    if (t==0){
      u64 c = pg-gg; u32 idx=(u32)(g*4+3);
      for (int q=0;q<4;q++){ u64 w=arr[g*4+q]; if (c+w>target){ idx=(u32)(g*4+q); break; } c+=w; }
      *out_idx = idx;
    }
  }
}

__device__ __forceinline__ void msmerge(float &m1, float &S1, float m2, float S2){
  float mm = fmaxf(m1, m2);
  if (mm == -INFINITY){ m1 = mm; S1 = 0.0f; return; }
  S1 = S1*__expf(m1-mm) + S2*__expf(m2-mm);
  m1 = mm;
}

// block argmax (comparator: larger value, then smaller idx) -> out[b] on winner
__device__ __forceinline__ void argmax_write(
    float best, u32 bi, float* wrf, u32* wru, int ln, int wv, int b, int* out)
{
  #pragma unroll
  for (int d=32; d>0; d>>=1){
    float c2=__shfl_down(best,d,64); u32 i2=__shfl_down(bi,d,64);
    if (c2>best || (c2==best && i2<bi)){best=c2;bi=i2;}
  }
  if (ln==0){ wrf[wv]=best; wru[wv]=bi; }
  __syncthreads();
  if (wv==0){
    float b1=(ln<NW)?wrf[ln]:-INFINITY; u32 i1=(ln<NW)?wru[ln]:0xFFFFFFFFu;
    #pragma unroll
    for (int d=32; d>0; d>>=1){
      float b2=__shfl_down(b1,d,64); u32 i2=__shfl_down(i1,d,64);
      if (b2>b1 || (b2==b1 && i2<i1)){b1=b2;i1=i2;}
    }
    if (ln==0) out[b]=(int)i1;
  }
}

// ---------- the fused kernel: one block per row, 2 full streams ----------
__global__ __launch_bounds__(BLK) void k_all(
    const float* __restrict__ logits, const float* __restrict__ temp,
    const float* __restrict__ minp, const int* __restrict__ topk,
    const float* __restrict__ topp, int* __restrict__ out)
{
  __shared__ u32 cnt[NB];          // 16KB
  __shared__ u64 mass[NB];         // 32KB
  __shared__ u64 aux64[BLK];       // 8KB (low half aliased as u32 aux)
  __shared__ u64 list[CAPL];       // 32KB: (key<<32)|idx
  __shared__ float wrf1[NW], wrf2[NW];
  __shared__ u32  wru1[NW];
  __shared__ float sh_m;
  __shared__ u32 sh_lstar, sh_K, sh_len, sh_acc1, sh_acc2;
  __shared__ u32 sh_idx, sh_bef32;
  __shared__ u64 sh_bef64, sh_tfix;

  u32* aux32 = (u32*)aux64;

  const int b = blockIdx.x;
  const int t = threadIdx.x;
  const int ln = t & 63, wv = t >> 6;
  const float T = temp[b];
  const float* row = logits + (size_t)b * VOCAB;
  const float4* row4 = (const float4*)row;

  // ======== greedy rows: argmax only (1 stream) ========
  if (T < SEPS){
    float M = -INFINITY; u32 Mi = 0xFFFFFFFFu;
    for (int i=t; i<NV4; i+=BLK){
      float4 q = row4[i];
      #pragma unroll
      for (int j=0;j<4;j++){
        float l = (&q.x)[j]; u32 gi = (u32)(i*4+j);
        if (l > M){ M = l; Mi = gi; }
      }
    }
    argmax_write(M, Mi, wrf1, wru1, ln, wv, b, out);
    return;
  }

  // ======== P1: online (m,Z) + 12-bit all-token count hist ========
  const float invT = 1.0f / T;
  for (int i=t;i<NB;i+=BLK) cnt[i]=0u;
  if (t==0){ sh_K=0u; sh_len=0u; sh_acc1=0u; sh_acc2=0u; }
  __syncthreads();
  float ms = -INFINITY, S = 0.0f;
  for (int i=t; i<NV4; i+=2*BLK){
    float4 qa = row4[i];
    int i2 = i + BLK;
    bool h2 = (i2 < NV4);
    float4 qb;
    if (h2) qb = row4[i2];
    #pragma unroll
    for (int j=0;j<4;j++){
      float l = (&qa.x)[j];
      float s = l * invT;
      if (s > ms){ S = S*__expf(ms - s) + 1.0f; ms = s; }
      else       { S += __expf(s - ms); }
      atomicAdd(&cnt[f2key(l)>>20], 1u);
    }
    if (h2){
      #pragma unroll
      for (int j=0;j<4;j++){
        float l = (&qb.x)[j];
        float s = l * invT;
        if (s > ms){ S = S*__expf(ms - s) + 1.0f; ms = s; }
        else       { S += __expf(s - ms); }
        atomicAdd(&cnt[f2key(l)>>20], 1u);
      }
    }
  }
  #pragma unroll
  for (int d=32; d>0; d>>=1){
    float m2 = __shfl_down(ms, d, 64); float S2 = __shfl_down(S, d, 64);
    msmerge(ms, S, m2, S2);
  }
  if (ln==0){ wrf1[wv]=ms; wrf2[wv]=S; }
  __syncthreads();                       // also orders all P1 hist atomics
  if (wv==0){
    float m1 = (ln<NW)? wrf1[ln] : -INFINITY;
    float S1 = (ln<NW)? wrf2[ln] : 0.0f;
    #pragma unroll
    for (int d=32; d>0; d>>=1){
      float m2 = __shfl_down(m1, d, 64); float S2 = __shfl_down(S1, d, 64);
      msmerge(m1, S1, m2, S2);
    }
    if (ln==0){ sh_m = m1; wrf2[0] = S1; }
  }
  __syncthreads();
  const float m = sh_m, Z = wrf2[0];

  // top-k level-1 crossing over all-token counts
  int tk = topk[b]; if (tk < 1) tk = 1; if (tk > VOCAB) tk = VOCAB;
  cross4096_u32(cnt, aux32, (u32)(VOCAB - tk), &sh_idx, &sh_bef32, t);
  __syncthreads();
  const u32 b1k = sh_idx;
  const u32 r1  = (u32)(VOCAB - tk + 1) - sh_bef32;

  // min-p raw cutoff l* (monotone predicate, 32-step binary search)
  if (t==0){
    float rhs = minp[b] * (1.0f / Z);
    u32 lo = 0u, hi = 0xFF800000u;   // key(+inf)
    while (lo < hi){
      u32 mid = lo + ((hi - lo) >> 1);
      float e = __expf(key2f(mid) * invT - m);
      if ((e / Z) >= rhs) hi = mid; else lo = mid + 1u;
    }
    sh_lstar = lo;
  }
  __syncthreads();
  const u32 lstar = sh_lstar;
  const u32 bl = lstar >> 20;

  // Kmin = #tokens in buckets > bl;  sC = #tokens in buckets >= b1k
  {
    u32 pa=0u, pc=0u;
    for (int i=t;i<NB;i+=BLK){
      u32 c = cnt[i];
      if ((u32)i > bl)   pa += c;
      if ((u32)i >= b1k) pc += c;
    }
    #pragma unroll
    for (int d=32; d>0; d>>=1){ pa += __shfl_down(pa,d,64); pc += __shfl_down(pc,d,64); }
    if (ln==0){ atomicAdd(&sh_acc1, pa); atomicAdd(&sh_acc2, pc); }
  }
  __syncthreads();
  const u32 Kmin  = sh_acc1;
  const u32 cntbl = cnt[bl];
  const bool kcert = (Kmin >= (u32)tk);        // kval certain from hist alone
  const u32 CLB = kcert ? b1k : bl;            // ambiguous case: b1k == bl (proven)
  const u32 listlen = kcert ? sh_acc2 : (Kmin + cntbl);
  const bool fastOK = (listlen <= (u32)CAPL);

  // ======== P2: kept-only mass hist + K count + (key,idx) compaction ========
  for (int i=t;i<NB;i+=BLK) mass[i]=0ull;
  __syncthreads();
  u32 kc = 0u;
  for (int i=t; i<NV4; i+=2*BLK){
    float4 qa = row4[i];
    int i2 = i + BLK;
    bool h2 = (i2 < NV4);
    float4 qb;
    if (h2) qb = row4[i2];
    #pragma unroll
    for (int j=0;j<4;j++){
      float l = (&qa.x)[j];
      u32 key = f2key(l);
      if (key >= lstar){
        kc++;
        atomicAdd(&mass[key>>20], efix(__expf(l*invT - m)));
      }
      if (fastOK && (key>>20) >= CLB){
        u32 p = atomicAdd(&sh_len, 1u);
        list[p] = ((u64)key << 32) | (u64)(u32)(i*4+j);
      }
    }
    if (h2){
      #pragma unroll
      for (int j=0;j<4;j++){
        float l = (&qb.x)[j];
        u32 key = f2key(l);
        if (key >= lstar){
          kc++;
          atomicAdd(&mass[key>>20], efix(__expf(l*invT - m)));
        }
        if (fastOK && (key>>20) >= CLB){
          u32 p = atomicAdd(&sh_len, 1u);
          list[p] = ((u64)key << 32) | (u64)(u32)(i2*4+j);
        }
      }
    }
  }
  #pragma unroll
  for (int d=32; d>0; d>>=1) kc += __shfl_down(kc, d, 64);
  if (ln==0) atomicAdd(&sh_K, kc);
  __syncthreads();
  const u32 K = sh_K;
  const bool kval = (K >= (u32)tk);
  cross4096_mass(mass, aux64, topp[b], &sh_tfix, &sh_idx, &sh_bef64, t);
  __syncthreads();
  const u32 b1p = sh_idx;
  const u64 t1  = sh_tfix - sh_bef64;
  const u32 llen = sh_len;
  const bool needK = kval && (b1p <= b1k);     // b1p<b1k => thr=kkey; ==: both
  const bool needP = (!kval) || (b1p >= b1k);  // b1p>b1k => thr=pkey

  u32 kkey = 0u, pkey = 0u;

  if (fastOK){
    // ---- in-LDS refinement on the compacted list ----
    if (needK){
      for (int i=t;i<NB;i+=BLK) cnt[i]=0u;
      __syncthreads();
      for (u32 i=t; i<llen; i+=BLK){
        u32 key = (u32)(list[i]>>32);
        if ((key>>20) == b1k) atomicAdd(&cnt[(key>>8)&0xFFFu], 1u);
      }
      __syncthreads();
      cross4096_u32(cnt, aux32, r1-1u, &sh_idx, &sh_bef32, t);
      __syncthreads();
      u32 b2k = sh_idx, r2 = r1 - sh_bef32;
      u32 prefk = (b1k<<12) | b2k;
      for (int i=t;i<256;i+=BLK) cnt[i]=0u;
      __syncthreads();
      for (u32 i=t; i<llen; i+=BLK){
        u32 key = (u32)(list[i]>>32);
        if ((key>>8) == prefk) atomicAdd(&cnt[key&0xFFu], 1u);
      }
      __syncthreads();
      cross256_u32(cnt, r2-1u, &sh_idx, t);
      __syncthreads();
      kkey = (prefk<<8) | sh_idx;
    }
    if (needP){
      for (int i=t;i<NB;i+=BLK) mass[i]=0ull;
      __syncthreads();
      for (u32 i=t; i<llen; i+=BLK){
        u32 key = (u32)(list[i]>>32);
        if ((key>>20) == b1p && key >= lstar)
          atomicAdd(&mass[(key>>8)&0xFFFu], efix(__expf(key2f(key)*invT - m)));
      }
      __syncthreads();
      cross4096_u64(mass, aux64, t1, &sh_idx, &sh_bef64, t);
      __syncthreads();
      u32 b2p = sh_idx; u64 t2 = t1 - sh_bef64;
      u32 prefp = (b1p<<12) | b2p;
      for (int i=t;i<256;i+=BLK) mass[i]=0ull;
      __syncthreads();
      for (u32 i=t; i<llen; i+=BLK){
        u32 key = (u32)(list[i]>>32);
        if ((key>>8) == prefp && key >= lstar)
          atomicAdd(&mass[key&0xFFu], efix(__expf(key2f(key)*invT - m)));
      }
      __syncthreads();
      cross256_u64(mass, t2, &sh_idx, t);
      __syncthreads();
      pkey = (prefp<<8) | sh_idx;
    }
    const u32 thrkey = kkey > pkey ? kkey : pkey;

    // ---- sampling over list (survivors = {key >= thrkey}, <= ~63) ----
    float best = -INFINITY; u32 bi = 0xFFFFFFFFu;
    for (u32 i=t; i<llen; i+=BLK){
      u64 e = list[i];
      u32 key = (u32)(e>>32);
      if (key >= thrkey){
        u32 idx = (u32)e;
        u32 c = (u32)b * (u32)VOCAB + idx;
        float cand = key2f(key)*invT + bits2gumbel(gumbel_bits(c));
        if (cand > best || (cand == best && idx < bi)){ best = cand; bi = idx; }
      }
    }
    argmax_write(best, bi, wrf1, wru1, ln, wv, b, out);
    return;
  }

  // ======== slow path (list overflow): full-stream refinement + sampling ========
  for (int i=t;i<NB;i+=BLK){ cnt[i]=0u; mass[i]=0ull; }
  __syncthreads();
  for (int i=t; i<NV4; i+=BLK){
    float4 q = row4[i];
    #pragma unroll
    for (int j=0;j<4;j++){
      float l = (&q.x)[j]; u32 key = f2key(l); u32 hi = key>>20;
      if (kval && hi == b1k) atomicAdd(&cnt[(key>>8)&0xFFFu], 1u);
      if (hi == b1p && key >= lstar)
        atomicAdd(&mass[(key>>8)&0xFFFu], efix(__expf(l*invT - m)));
    }
  }
  __syncthreads();
  cross4096_u32(cnt, aux32, r1-1u, &sh_idx, &sh_bef32, t);
  __syncthreads();
  u32 b2k = sh_idx, r2 = r1 - sh_bef32;
  cross4096_u64(mass, aux64, t1, &sh_idx, &sh_bef64, t);
  __syncthreads();
  u32 b2p = sh_idx; u64 t2 = t1 - sh_bef64;
  for (int i=t;i<256;i+=BLK){ cnt[i]=0u; mass[i]=0ull; }
  __syncthreads();
  for (int i=t; i<NV4; i+=BLK){
    float4 q = row4[i];
    #pragma unroll
    for (int j=0;j<4;j++){
      float l = (&q.x)[j]; u32 key = f2key(l);
      if (kval && (key>>8)==(((b1k<<12)|b2k)))
        atomicAdd(&cnt[key&0xFFu], 1u);
      if ((key>>8)==(((b1p<<12)|b2p)) && key >= lstar)
        atomicAdd(&mass[key&0xFFu], efix(__expf(l*invT - m)));
    }
  }
  __syncthreads();
  cross256_u32(cnt, r2-1u, &sh_idx, t);
  __syncthreads();
  if (kval) kkey = (b1k<<20)|(b2k<<8)|sh_idx;
  cross256_u64(mass, t2, &sh_idx, t);
  __syncthreads();
  pkey = (b1p<<20)|(b2p<<8)|sh_idx;
  const float thrf = key2f(kkey > pkey ? kkey : pkey);

  float best = -INFINITY; u32 bi = 0xFFFFFFFFu;
  for (int i=t; i<NV4; i+=BLK){
    float4 q = row4[i];
    #pragma unroll
    for (int j=0;j<4;j++){
      float l = (&q.x)[j];
      if (l >= thrf){
        u32 idx = (u32)(i*4+j);
        u32 c = (u32)b * (u32)VOCAB + idx;
        float cand = l*invT + bits2gumbel(gumbel_bits(c));
        if (cand > best || (cand == best && idx < bi)){ best = cand; bi = idx; }
      }
    }
  }
  argmax_write(best, bi, wrf1, wru1, ln, wv, b, out);
}

extern "C" void kernel_launch(void* const* d_in, const int* in_sizes, int n_in,
                              void* d_out, int out_size, void* d_ws, size_t ws_size,
                              hipStream_t stream)
{
  const float* logits = (const float*)d_in[0];
  const float* temp   = (const float*)d_in[1];
  const float* minp   = (const float*)d_in[2];
  const int*   topk   = (const int*)d_in[3];
  const float* topp   = (const float*)d_in[4];
  int* out = (int*)d_out;

  hipLaunchKernelGGL(k_all, dim3(NROWS), dim3(BLK), 0, stream,
                     logits, temp, minp, topk, topp, out);
}